// Round 5
// baseline (199.570 us; speedup 1.0000x reference)
//
#include <hip/hip_runtime.h>
#include <math.h>

// Problem constants
#define XD 128
#define YD 128
#define ZD 8
#define ED 64
#define KD 3
#define NITER 3
#define FHD 96
#define FWD 320
#define HALF_W 640.0f
#define HALF_H 192.0f

#define AFS  68    // floats per A/union row (272 B)
#define DSTR 28    // floats per logit-tile row
#define HSTR 66    // floats per H-tile row

// per-wave LDS region offsets (bytes); all regions float-family
#define OFF_UNI  0       // union: A-tile fp32 (16*68*4=4352) / Db (16*28*4) / Hb (16*66*4=4224)
#define OFF_SD   4352    // 48 int4  = 768
#define OFF_SW   5120    // 48 float4 = 768
#define OFF_CXY  5888    // 32 floats = 128
#define WAVE_LDS 6016

typedef __attribute__((ext_vector_type(8))) short short8;
typedef __attribute__((ext_vector_type(4))) float f32x4;
typedef float __attribute__((may_alias)) fal;
typedef int   __attribute__((may_alias)) ial;

__device__ __forceinline__ unsigned short f2bf(float f) {
    unsigned u = __float_as_uint(f);
    u += 0x7fff + ((u >> 16) & 1);
    return (unsigned short)(u >> 16);
}

// pack two fp32 -> one int holding (bf16(f0) | bf16(f1)<<16), RNE
__device__ __forceinline__ int packbf2(float f0, float f1) {
    unsigned u0 = __float_as_uint(f0), u1 = __float_as_uint(f1);
    u0 += 0x7fffu + ((u0 >> 16) & 1u);
    u1 += 0x7fffu + ((u1 >> 16) & 1u);
    return (int)((u0 >> 16) | (u1 & 0xffff0000u));
}

// load 8 consecutive fp32 from LDS row and pack to an MFMA bf16 A-fragment
__device__ __forceinline__ short8 load_a(const fal* U, int row, int koff) {
    f32x4 p0 = *(const f32x4*)(U + row * AFS + koff);
    f32x4 p1 = *(const f32x4*)(U + row * AFS + koff + 4);
    union { short8 s; int i[4]; } r;
    r.i[0] = packbf2(p0[0], p0[1]);
    r.i[1] = packbf2(p0[2], p0[3]);
    r.i[2] = packbf2(p1[0], p1[1]);
    r.i[3] = packbf2(p1[2], p1[3]);
    return r.s;
}

// sum over the 16-lane DPP row (lanes grouped by m16) via row_ror 1,2,4,8
__device__ __forceinline__ float rowsum16(float v) {
    v += __int_as_float(__builtin_amdgcn_update_dpp(0, __float_as_int(v), 0x121, 0xf, 0xf, true));
    v += __int_as_float(__builtin_amdgcn_update_dpp(0, __float_as_int(v), 0x122, 0xf, 0xf, true));
    v += __int_as_float(__builtin_amdgcn_update_dpp(0, __float_as_int(v), 0x124, 0xf, 0xf, true));
    v += __int_as_float(__builtin_amdgcn_update_dpp(0, __float_as_int(v), 0x128, 0xf, 0xf, true));
    return v;
}

// -------- prep: img CHW->HWC transpose (blocks 0..479) + weight frags (480+) ------
__global__ __launch_bounds__(256) void k_prep(const float* __restrict__ img,
                                              float* __restrict__ outHWC,
                                              const float* __restrict__ W_off,
                                              const float* __restrict__ W_w,
                                              const float* __restrict__ W_l,
                                              unsigned short* __restrict__ W9f,
                                              unsigned short* __restrict__ Wlf) {
    if (blockIdx.x < (FHD * FWD) / 64) {
        __shared__ float tile[64][65];
        const int hw0 = blockIdx.x * 64;
        const int lane = threadIdx.x & 63;
        const int r = threadIdx.x >> 6;
#pragma unroll
        for (int i = 0; i < 16; ++i) {
            int e = r + 4 * i;
            tile[e][lane] = img[e * (FHD * FWD) + hw0 + lane];
        }
        __syncthreads();
#pragma unroll
        for (int i = 0; i < 16; ++i) {
            int row = r + 4 * i;
            outHWC[(hw0 + row) * 64 + lane] = tile[lane][row];
        }
    } else {
        int idx = (blockIdx.x - (FHD * FWD) / 64) * 256 + threadIdx.x;
        if (idx < 3 * 4 * 2 * 64) {
            int lane = idx & 63, s = (idx >> 6) & 1, t = (idx >> 7) & 3, i = idx >> 9;
            int n = t * 16 + (lane & 15), quad = lane >> 4;
#pragma unroll
            for (int jj = 0; jj < 8; ++jj) {
                int ep = s * 32 + quad * 8 + jj;
                Wlf[idx * 8 + jj] = f2bf(W_l[(i * ED + ep) * ED + n]);
            }
        } else if (idx < 3 * 4 * 2 * 64 + 3 * 2 * 64) {
            int k = idx - 3 * 4 * 2 * 64;
            int lane = k & 63, s = (k >> 6) & 1, i = k >> 7;
            int n = lane & 15, quad = lane >> 4;
#pragma unroll
            for (int jj = 0; jj < 8; ++jj) {
                int ep = s * 32 + quad * 8 + jj;
                float v = 0.0f;
                if (n < 6) v = W_off[(i * ED + ep) * 6 + n];
                else if (n < 9) v = W_w[(i * ED + ep) * 3 + (n - 6)];
                W9f[k * 8 + jj] = f2bf(v);
            }
        }
    }
}

// ---- main fused kernel: wave = 2 points, block = 8 points, writes out directly ----
__global__ __launch_bounds__(256, 4) void k_main(
    const float* __restrict__ Tv,     // (3,4)
    const float* __restrict__ intr,   // (3,3)
    const float* __restrict__ imgHWC, // (FH*FW, E)
    const float* __restrict__ bev_in, // (X,Y,Z,E)
    const unsigned short* __restrict__ W9f,
    const unsigned short* __restrict__ Wlf,
    const float* __restrict__ b_off,  // (I,6)
    const float* __restrict__ s_off,  // (I,)
    const float* __restrict__ b_w,    // (I,3)
    const float* __restrict__ b_l,    // (I,E)
    const float* __restrict__ ln_g,   // (I,E)
    const float* __restrict__ ln_b,   // (I,E)
    float* __restrict__ out)          // (E, Y*X)
{
    __shared__ __align__(16) char smem[4 * WAVE_LDS];
    __shared__ __align__(16) float Ob[8][64];

    const int lane = threadIdx.x & 63;
    const int wv = threadIdx.x >> 6;
    const int wid2 = __builtin_amdgcn_readfirstlane(blockIdx.x * 4 + wv);
    const int m16 = lane & 15;
    const int quad = lane >> 4;

    char* base = smem + wv * WAVE_LDS;
    fal*  U   = (fal*)(base + OFF_UNI);   // A-tile / Db / Hb (serial lifetimes)
    ial*  Sd  = (ial*)(base + OFF_SD);
    fal*  Sw  = (fal*)(base + OFF_SW);
    fal*  Cxy = (fal*)(base + OFF_CXY);

    // T = intr @ Tv (3x4), uniform
    float T[12];
#pragma unroll
    for (int r = 0; r < 3; ++r)
#pragma unroll
        for (int c = 0; c < 4; ++c)
            T[r * 4 + c] = intr[r * 3 + 0] * Tv[0 * 4 + c] +
                           intr[r * 3 + 1] * Tv[1 * 4 + c] +
                           intr[r * 3 + 2] * Tv[2 * 4 + c];

    // two points per wave; rows m = p*8 + z; cx/cy stashed in LDS
    float bev[16];
#pragma unroll
    for (int p = 0; p < 2; ++p) {
        int q = 2 * wid2 + p;
        int x = q & (XD - 1);
        int y = q >> 7;
        float gx = x * 0.8f;
        float gy = 51.2f - y * 0.8f;
        int pbase = (((x << 7) | y) << 9);
#pragma unroll
        for (int z = 0; z < ZD; ++z) {
            float gz = z * 0.5f - 2.5f;
            float p0 = T[0] * gx + T[1] * gy + T[2] * gz + T[3];
            float p1 = T[4] * gx + T[5] * gy + T[6] * gz + T[7];
            float p2 = T[8] * gx + T[9] * gy + T[10] * gz + T[11];
            float cxv = (p0 / p2) / HALF_W - 1.0f;
            float cyv = (p1 / p2) / HALF_H - 1.0f;
            int m = p * 8 + z;
            if (lane == 0) {
                Cxy[m * 2 + 0] = cxv;
                Cxy[m * 2 + 1] = cyv;
            }
            bev[m] = bev_in[pbase + z * ED + lane];
        }
    }

    for (int i = 0; i < NITER; ++i) {
        // ---- stage 1: logits = bev(16x64) @ W9(64x9) via 2 MFMAs ----
#pragma unroll
        for (int m = 0; m < 16; ++m) U[m * AFS + lane] = bev[m];

        short8 wb0 = *(const short8*)(W9f + ((i * 2 + 0) * 64 + lane) * 8);
        short8 wb1 = *(const short8*)(W9f + ((i * 2 + 1) * 64 + lane) * 8);
        short8 a0 = load_a(U, m16, quad * 8);
        short8 a1 = load_a(U, m16, 32 + quad * 8);
        f32x4 dlog = {0.0f, 0.0f, 0.0f, 0.0f};
        dlog = __builtin_amdgcn_mfma_f32_16x16x32_bf16(a0, wb0, dlog, 0, 0, 0);
        dlog = __builtin_amdgcn_mfma_f32_16x16x32_bf16(a1, wb1, dlog, 0, 0, 0);
        // D-layout: row quad*4+r, col m16 (overwrites A-tile; A consumed)
#pragma unroll
        for (int r = 0; r < 4; ++r) U[(quad * 4 + r) * DSTR + m16] = dlog[r];

        const float so = s_off[i];
        const float bo0 = b_off[i * 6 + 0], bo1 = b_off[i * 6 + 1], bo2 = b_off[i * 6 + 2];
        const float bo3 = b_off[i * 6 + 3], bo4 = b_off[i * 6 + 4], bo5 = b_off[i * 6 + 5];
        const float bw0 = b_w[i * 3 + 0], bw1 = b_w[i * 3 + 1], bw2 = b_w[i * 3 + 2];

        // ---- lane-parallel sample descriptors (48 lanes = 16 rows x 3 k) ----
        if (lane < 48) {
            int m = lane / 3;
            int k = lane - m * 3;
            const fal* Dm = U + m * DSTR;
            f32x4 qa = *(const f32x4*)(Dm);       // logits 0..3
            f32x4 qb = *(const f32x4*)(Dm + 4);   // logits 4..7
            float l8 = Dm[8];

            float ox0 = (qa[0] + bo0) * so, oy0 = (qa[1] + bo1) * so;
            float ox1 = (qa[2] + bo2) * so, oy1 = (qa[3] + bo3) * so;
            float ox2 = (qb[0] + bo4) * so, oy2 = (qb[1] + bo5) * so;
            float l0 = qb[2] + bw0, l1 = qb[3] + bw1, l2 = l8 + bw2;
            float mx = fmaxf(fmaxf(l0, l1), l2);
            float e0 = __expf(l0 - mx), e1 = __expf(l1 - mx), e2 = __expf(l2 - mx);
            float inv = 1.0f / (e0 + e1 + e2);
            float wk0 = e0 * inv, wk1 = e1 * inv, wk2 = e2 * inv;

            float wkk = (k == 0) ? wk0 : ((k == 1) ? wk1 : wk2);
            float ox  = (k == 0) ? ox0 : ((k == 1) ? ox1 : ox2);
            float oy  = (k == 0) ? oy0 : ((k == 1) ? oy1 : oy2);

            float cxf = Cxy[m * 2 + 0], cyf = Cxy[m * 2 + 1];
            float gxx = cxf + ox, gyy = cyf + oy;
            float px = ((gxx + 1.0f) * (float)FWD - 1.0f) * 0.5f;
            float py = ((gyy + 1.0f) * (float)FHD - 1.0f) * 0.5f;
            float x0f = floorf(px), y0f = floorf(py);
            float fx = px - x0f, fy = py - y0f;
            int ix0 = (int)x0f, iy0 = (int)y0f;
            int ix1 = ix0 + 1, iy1 = iy0 + 1;
            float mx0 = (ix0 >= 0 && ix0 < FWD) ? 1.0f : 0.0f;
            float mx1 = (ix1 >= 0 && ix1 < FWD) ? 1.0f : 0.0f;
            float my0 = (iy0 >= 0 && iy0 < FHD) ? 1.0f : 0.0f;
            float my1 = (iy1 >= 0 && iy1 < FHD) ? 1.0f : 0.0f;
            int cx0 = min(max(ix0, 0), FWD - 1);
            int cx1 = min(max(ix1, 0), FWD - 1);
            int cy0 = min(max(iy0, 0), FHD - 1);
            int cy1 = min(max(iy1, 0), FHD - 1);
            int r0 = cy0 * FWD, r1 = cy1 * FWD;
            float wx1 = fx, wx0 = 1.0f - fx;
            float wy1 = fy, wy0 = 1.0f - fy;
            ial* sd = Sd + lane * 4;
            sd[0] = r0 + cx0; sd[1] = r0 + cx1; sd[2] = r1 + cx0; sd[3] = r1 + cx1;
            fal* sw = Sw + lane * 4;
            sw[0] = wkk * wx0 * wy0 * mx0 * my0;
            sw[1] = wkk * wx1 * wy0 * mx1 * my0;
            sw[2] = wkk * wx0 * wy1 * mx0 * my1;
            sw[3] = wkk * wx1 * wy1 * mx1 * my1;
        }

        // ---- sampling: 48 samples, broadcast descriptors, 4 coalesced loads each --
        float b2[16];
#pragma unroll
        for (int m = 0; m < 16; ++m) {
            float feat = 0.0f;
#pragma unroll
            for (int k = 0; k < KD; ++k) {
                int s = m * 3 + k;
                int4 id = *(const int4*)(Sd + s * 4);
                float4 w4 = *(const float4*)(Sw + s * 4);
                feat = fmaf(w4.x, imgHWC[(unsigned)((id.x << 6) + lane)], feat);
                feat = fmaf(w4.y, imgHWC[(unsigned)((id.y << 6) + lane)], feat);
                feat = fmaf(w4.z, imgHWC[(unsigned)((id.z << 6) + lane)], feat);
                feat = fmaf(w4.w, imgHWC[(unsigned)((id.w << 6) + lane)], feat);
            }
            b2[m] = bev[m] + feat;  // bev_mid
        }

        // ---- stage 2: h = bev_mid(16x64) @ W_l + b_l via 8 MFMAs ----
#pragma unroll
        for (int m = 0; m < 16; ++m) U[m * AFS + lane] = b2[m];
        short8 a0b = load_a(U, m16, quad * 8);
        short8 a1b = load_a(U, m16, 32 + quad * 8);
        f32x4 accs[4];
#pragma unroll
        for (int t = 0; t < 4; ++t) {
            float bb = b_l[i * ED + t * 16 + m16];
            f32x4 acc = {bb, bb, bb, bb};
            short8 w0 = *(const short8*)(Wlf + (((i * 4 + t) * 2 + 0) * 64 + lane) * 8);
            short8 w1 = *(const short8*)(Wlf + (((i * 4 + t) * 2 + 1) * 64 + lane) * 8);
            acc = __builtin_amdgcn_mfma_f32_16x16x32_bf16(a0b, w0, acc, 0, 0, 0);
            acc = __builtin_amdgcn_mfma_f32_16x16x32_bf16(a1b, w1, acc, 0, 0, 0);
            accs[t] = acc;
        }

        // ---- LayerNorm in D-layout: rows quad*4+r, cols t*16+m16 (DPP row-sums) ----
        float s1[4], s2[4];
#pragma unroll
        for (int r = 0; r < 4; ++r) {
            s1[r] = accs[0][r] + accs[1][r] + accs[2][r] + accs[3][r];
            s2[r] = accs[0][r] * accs[0][r];
            s2[r] = fmaf(accs[1][r], accs[1][r], s2[r]);
            s2[r] = fmaf(accs[2][r], accs[2][r], s2[r]);
            s2[r] = fmaf(accs[3][r], accs[3][r], s2[r]);
            s1[r] = rowsum16(s1[r]);
            s2[r] = rowsum16(s2[r]);
        }
        float gt[4], bt[4];
#pragma unroll
        for (int t = 0; t < 4; ++t) {
            gt[t] = ln_g[i * ED + t * 16 + m16];
            bt[t] = ln_b[i * ED + t * 16 + m16];
        }
#pragma unroll
        for (int r = 0; r < 4; ++r) {
            float mu = s1[r] * (1.0f / 64.0f);
            float var = fmaxf(s2[r] * (1.0f / 64.0f) - mu * mu, 0.0f);
            float rs = rsqrtf(var + 1e-5f);
            int row = quad * 4 + r;
#pragma unroll
            for (int t = 0; t < 4; ++t) {
                float hn = (accs[t][r] - mu) * rs * gt[t] + bt[t];
                U[row * HSTR + t * 16 + m16] = hn;   // Hb (overwrites A2; consumed)
            }
        }
        // residual back in lane=channel layout
#pragma unroll
        for (int m = 0; m < 16; ++m) bev[m] = b2[m] + U[m * HSTR + lane];
    }

    // ---- z-mean -> block LDS tile -> direct (E, Y*X) output ----
#pragma unroll
    for (int p = 0; p < 2; ++p) {
        float s = 0.0f;
#pragma unroll
        for (int z = 0; z < ZD; ++z) s += bev[p * 8 + z];
        Ob[wv * 2 + p][lane] = s * 0.125f;
    }
    __syncthreads();
    {
        const int q0 = __builtin_amdgcn_readfirstlane(blockIdx.x * 8);
        int t = threadIdx.x;
        int e = t >> 2, pr = t & 3;
        float2 o;
        o.x = Ob[2 * pr + 0][e];
        o.y = Ob[2 * pr + 1][e];
        *(float2*)(out + e * (YD * XD) + q0 + 2 * pr) = o;
    }
}

extern "C" void kernel_launch(void* const* d_in, const int* in_sizes, int n_in,
                              void* d_out, int out_size, void* d_ws, size_t ws_size,
                              hipStream_t stream) {
    const float* Tv      = (const float*)d_in[0];
    const float* intr    = (const float*)d_in[1];
    const float* img     = (const float*)d_in[2];
    const float* bev_in  = (const float*)d_in[3];
    const float* W_off   = (const float*)d_in[4];
    const float* b_off   = (const float*)d_in[5];
    const float* s_off   = (const float*)d_in[6];
    const float* W_w     = (const float*)d_in[7];
    const float* b_w     = (const float*)d_in[8];
    const float* W_l     = (const float*)d_in[9];
    const float* b_l     = (const float*)d_in[10];
    const float* ln_g    = (const float*)d_in[11];
    const float* ln_b    = (const float*)d_in[12];
    float* out = (float*)d_out;

    char* ws = (char*)d_ws;
    float* imgHWC = (float*)ws;                                  // 7,864,320 B
    unsigned short* W9f = (unsigned short*)(ws + 7864320);       // 6,144 B
    unsigned short* Wlf = (unsigned short*)(ws + 7864320 + 6144);// 24,576 B

    // prep: img transpose (480 blocks) + weight frags (8 blocks)
    k_prep<<<(FHD * FWD) / 64 + 8, 256, 0, stream>>>(img, imgHWC, W_off, W_w, W_l,
                                                     W9f, Wlf);
    // main fused loop: 2048 blocks x 4 waves x 2 points; writes (E,Y*X) directly
    k_main<<<(XD * YD) / 8, 256, 0, stream>>>(Tv, intr, imgHWC, bev_in,
                                              W9f, Wlf, b_off, s_off, b_w,
                                              b_l, ln_g, ln_b, out);
}

// Round 6
// 198.985 us; speedup vs baseline: 1.0029x; 1.0029x over previous
//
#include <hip/hip_runtime.h>
#include <math.h>

// Problem constants
#define XD 128
#define YD 128
#define ZD 8
#define ED 64
#define KD 3
#define NITER 3
#define FHD 96
#define FWD 320
#define HALF_W 640.0f
#define HALF_H 192.0f

#define ASTRIDE 80   // shorts per A-tile row (160 B: 16B-aligned, zero-conflict measured R3/R4)
#define DSTR 28      // floats per logit-tile row
#define HSTR 68      // floats per H-tile row

// per-wave LDS region offsets (bytes)
// UNION region: Ab (16*80*2=2560) -> Db (16*28*4=1792) -> Ab -> Hb (16*68*4=4352),
// strictly serial wave-private lifetimes (LDS ops are in-order within a wave).
#define OFF_UNI  0
#define OFF_SD   4352    // 48 int4  = 768
#define OFF_SW   5120    // 48 float4 = 768
#define OFF_CXY  5888    // 32 floats = 128
#define WAVE_LDS 6016

typedef __attribute__((ext_vector_type(8))) short short8;
typedef __attribute__((ext_vector_type(4))) float f32x4;
typedef float          __attribute__((may_alias)) fal;
typedef int            __attribute__((may_alias)) ial;
typedef unsigned short __attribute__((may_alias)) usal;

__device__ __forceinline__ unsigned short f2bf(float f) {
    unsigned u = __float_as_uint(f);
    u += 0x7fff + ((u >> 16) & 1);
    return (unsigned short)(u >> 16);
}

// -------- prep: img CHW->HWC transpose (blocks 0..479) + weight frags (480+) ------
__global__ __launch_bounds__(256) void k_prep(const float* __restrict__ img,
                                              float* __restrict__ outHWC,
                                              const float* __restrict__ W_off,
                                              const float* __restrict__ W_w,
                                              const float* __restrict__ W_l,
                                              unsigned short* __restrict__ W9f,
                                              unsigned short* __restrict__ Wlf) {
    if (blockIdx.x < (FHD * FWD) / 64) {
        __shared__ float tile[64][65];
        const int hw0 = blockIdx.x * 64;
        const int lane = threadIdx.x & 63;
        const int r = threadIdx.x >> 6;
#pragma unroll
        for (int i = 0; i < 16; ++i) {
            int e = r + 4 * i;
            tile[e][lane] = img[e * (FHD * FWD) + hw0 + lane];
        }
        __syncthreads();
#pragma unroll
        for (int i = 0; i < 16; ++i) {
            int row = r + 4 * i;
            outHWC[(hw0 + row) * 64 + lane] = tile[lane][row];
        }
    } else {
        int idx = (blockIdx.x - (FHD * FWD) / 64) * 256 + threadIdx.x;
        if (idx < 3 * 4 * 2 * 64) {
            int lane = idx & 63, s = (idx >> 6) & 1, t = (idx >> 7) & 3, i = idx >> 9;
            int n = t * 16 + (lane & 15), quad = lane >> 4;
#pragma unroll
            for (int jj = 0; jj < 8; ++jj) {
                int ep = s * 32 + quad * 8 + jj;
                Wlf[idx * 8 + jj] = f2bf(W_l[(i * ED + ep) * ED + n]);
            }
        } else if (idx < 3 * 4 * 2 * 64 + 3 * 2 * 64) {
            int k = idx - 3 * 4 * 2 * 64;
            int lane = k & 63, s = (k >> 6) & 1, i = k >> 7;
            int n = lane & 15, quad = lane >> 4;
#pragma unroll
            for (int jj = 0; jj < 8; ++jj) {
                int ep = s * 32 + quad * 8 + jj;
                float v = 0.0f;
                if (n < 6) v = W_off[(i * ED + ep) * 6 + n];
                else if (n < 9) v = W_w[(i * ED + ep) * 3 + (n - 6)];
                W9f[k * 8 + jj] = f2bf(v);
            }
        }
    }
}

// ---- main fused kernel: wave = 2 points, block = 8 points, writes out directly ----
__global__ __launch_bounds__(256, 6) void k_main(
    const float* __restrict__ Tv,     // (3,4)
    const float* __restrict__ intr,   // (3,3)
    const float* __restrict__ imgHWC, // (FH*FW, E)
    const float* __restrict__ bev_in, // (X,Y,Z,E)
    const unsigned short* __restrict__ W9f,
    const unsigned short* __restrict__ Wlf,
    const float* __restrict__ b_off,  // (I,6)
    const float* __restrict__ s_off,  // (I,)
    const float* __restrict__ b_w,    // (I,3)
    const float* __restrict__ b_l,    // (I,E)
    const float* __restrict__ ln_g,   // (I,E)
    const float* __restrict__ ln_b,   // (I,E)
    float* __restrict__ out)          // (E, Y*X)
{
    __shared__ __align__(16) char smem[4 * WAVE_LDS];
    __shared__ __align__(16) float Ob[8][65];   // padded: kills 4-way read conflict

    const int lane = threadIdx.x & 63;
    const int wv = threadIdx.x >> 6;
    const int wid2 = __builtin_amdgcn_readfirstlane(blockIdx.x * 4 + wv);
    const int m16 = lane & 15;
    const int quad = lane >> 4;

    char* base = smem + wv * WAVE_LDS;
    usal* Ab  = (usal*)(base + OFF_UNI);   // bf16 A-tile (union)
    fal*  Db  = (fal*)(base + OFF_UNI);    // fp32 logit tile (union)
    fal*  Hb  = (fal*)(base + OFF_UNI);    // fp32 h tile (union)
    ial*  Sd  = (ial*)(base + OFF_SD);
    fal*  Sw  = (fal*)(base + OFF_SW);
    fal*  Cxy = (fal*)(base + OFF_CXY);

    // T = intr @ Tv (3x4), uniform
    float T[12];
#pragma unroll
    for (int r = 0; r < 3; ++r)
#pragma unroll
        for (int c = 0; c < 4; ++c)
            T[r * 4 + c] = intr[r * 3 + 0] * Tv[0 * 4 + c] +
                           intr[r * 3 + 1] * Tv[1 * 4 + c] +
                           intr[r * 3 + 2] * Tv[2 * 4 + c];

    // two points per wave; rows m = p*8 + z; cx/cy stashed in LDS
    float bev[16];
#pragma unroll
    for (int p = 0; p < 2; ++p) {
        int q = 2 * wid2 + p;
        int x = q & (XD - 1);
        int y = q >> 7;
        float gx = x * 0.8f;
        float gy = 51.2f - y * 0.8f;
        int pbase = (((x << 7) | y) << 9);
#pragma unroll
        for (int z = 0; z < ZD; ++z) {
            float gz = z * 0.5f - 2.5f;
            float p0 = T[0] * gx + T[1] * gy + T[2] * gz + T[3];
            float p1 = T[4] * gx + T[5] * gy + T[6] * gz + T[7];
            float p2 = T[8] * gx + T[9] * gy + T[10] * gz + T[11];
            float cxv = (p0 / p2) / HALF_W - 1.0f;
            float cyv = (p1 / p2) / HALF_H - 1.0f;
            int m = p * 8 + z;
            if (lane == 0) {
                Cxy[m * 2 + 0] = cxv;
                Cxy[m * 2 + 1] = cyv;
            }
            bev[m] = bev_in[pbase + z * ED + lane];
        }
    }

    for (int i = 0; i < NITER; ++i) {
        // ---- stage 1: logits = bev(16x64) @ W9(64x9) via 2 MFMAs ----
#pragma unroll
        for (int m = 0; m < 16; ++m) Ab[m * ASTRIDE + lane] = f2bf(bev[m]);

        short8 wb0 = *(const short8*)(W9f + ((i * 2 + 0) * 64 + lane) * 8);
        short8 wb1 = *(const short8*)(W9f + ((i * 2 + 1) * 64 + lane) * 8);
        short8 a0 = *(const short8*)(Ab + m16 * ASTRIDE + quad * 8);
        short8 a1 = *(const short8*)(Ab + m16 * ASTRIDE + 32 + quad * 8);
        f32x4 dlog = {0.0f, 0.0f, 0.0f, 0.0f};
        dlog = __builtin_amdgcn_mfma_f32_16x16x32_bf16(a0, wb0, dlog, 0, 0, 0);
        dlog = __builtin_amdgcn_mfma_f32_16x16x32_bf16(a1, wb1, dlog, 0, 0, 0);
        // D-layout: row quad*4+r, col m16 (overwrites A-tile; A consumed)
#pragma unroll
        for (int r = 0; r < 4; ++r) Db[(quad * 4 + r) * DSTR + m16] = dlog[r];

        const float so = s_off[i];
        const float bo0 = b_off[i * 6 + 0], bo1 = b_off[i * 6 + 1], bo2 = b_off[i * 6 + 2];
        const float bo3 = b_off[i * 6 + 3], bo4 = b_off[i * 6 + 4], bo5 = b_off[i * 6 + 5];
        const float bw0 = b_w[i * 3 + 0], bw1 = b_w[i * 3 + 1], bw2 = b_w[i * 3 + 2];

        // ---- lane-parallel sample descriptors (48 lanes = 16 rows x 3 k) ----
        if (lane < 48) {
            int m = lane / 3;
            int k = lane - m * 3;
            const fal* Dm = Db + m * DSTR;
            f32x4 qa = *(const f32x4*)(Dm);       // logits 0..3
            f32x4 qb = *(const f32x4*)(Dm + 4);   // logits 4..7
            float l8 = Dm[8];

            float ox0 = (qa[0] + bo0) * so, oy0 = (qa[1] + bo1) * so;
            float ox1 = (qa[2] + bo2) * so, oy1 = (qa[3] + bo3) * so;
            float ox2 = (qb[0] + bo4) * so, oy2 = (qb[1] + bo5) * so;
            float l0 = qb[2] + bw0, l1 = qb[3] + bw1, l2 = l8 + bw2;
            float mx = fmaxf(fmaxf(l0, l1), l2);
            float e0 = __expf(l0 - mx), e1 = __expf(l1 - mx), e2 = __expf(l2 - mx);
            float inv = 1.0f / (e0 + e1 + e2);
            float wk0 = e0 * inv, wk1 = e1 * inv, wk2 = e2 * inv;

            float wkk = (k == 0) ? wk0 : ((k == 1) ? wk1 : wk2);
            float ox  = (k == 0) ? ox0 : ((k == 1) ? ox1 : ox2);
            float oy  = (k == 0) ? oy0 : ((k == 1) ? oy1 : oy2);

            float cxf = Cxy[m * 2 + 0], cyf = Cxy[m * 2 + 1];
            float gxx = cxf + ox, gyy = cyf + oy;
            float px = ((gxx + 1.0f) * (float)FWD - 1.0f) * 0.5f;
            float py = ((gyy + 1.0f) * (float)FHD - 1.0f) * 0.5f;
            float x0f = floorf(px), y0f = floorf(py);
            float fx = px - x0f, fy = py - y0f;
            int ix0 = (int)x0f, iy0 = (int)y0f;
            int ix1 = ix0 + 1, iy1 = iy0 + 1;
            float mx0 = (ix0 >= 0 && ix0 < FWD) ? 1.0f : 0.0f;
            float mx1 = (ix1 >= 0 && ix1 < FWD) ? 1.0f : 0.0f;
            float my0 = (iy0 >= 0 && iy0 < FHD) ? 1.0f : 0.0f;
            float my1 = (iy1 >= 0 && iy1 < FHD) ? 1.0f : 0.0f;
            int cx0 = min(max(ix0, 0), FWD - 1);
            int cx1 = min(max(ix1, 0), FWD - 1);
            int cy0 = min(max(iy0, 0), FHD - 1);
            int cy1 = min(max(iy1, 0), FHD - 1);
            int r0 = cy0 * FWD, r1 = cy1 * FWD;
            float wx1 = fx, wx0 = 1.0f - fx;
            float wy1 = fy, wy0 = 1.0f - fy;
            ial* sd = Sd + lane * 4;
            sd[0] = r0 + cx0; sd[1] = r0 + cx1; sd[2] = r1 + cx0; sd[3] = r1 + cx1;
            fal* sw = Sw + lane * 4;
            sw[0] = wkk * wx0 * wy0 * mx0 * my0;
            sw[1] = wkk * wx1 * wy0 * mx1 * my0;
            sw[2] = wkk * wx0 * wy1 * mx0 * my1;
            sw[3] = wkk * wx1 * wy1 * mx1 * my1;
        }

        // ---- sampling: 48 samples, broadcast descriptors, 4 coalesced loads each --
        float b2[16];
#pragma unroll
        for (int m = 0; m < 16; ++m) {
            float feat = 0.0f;
#pragma unroll
            for (int k = 0; k < KD; ++k) {
                int s = m * 3 + k;
                int4 id = *(const int4*)(Sd + s * 4);
                float4 w4 = *(const float4*)(Sw + s * 4);
                feat = fmaf(w4.x, imgHWC[(unsigned)((id.x << 6) + lane)], feat);
                feat = fmaf(w4.y, imgHWC[(unsigned)((id.y << 6) + lane)], feat);
                feat = fmaf(w4.z, imgHWC[(unsigned)((id.z << 6) + lane)], feat);
                feat = fmaf(w4.w, imgHWC[(unsigned)((id.w << 6) + lane)], feat);
            }
            b2[m] = bev[m] + feat;  // bev_mid
        }

        // ---- stage 2: h = bev_mid(16x64) @ W_l + b_l via 8 MFMAs ----
#pragma unroll
        for (int m = 0; m < 16; ++m) Ab[m * ASTRIDE + lane] = f2bf(b2[m]);
        short8 a0b = *(const short8*)(Ab + m16 * ASTRIDE + quad * 8);
        short8 a1b = *(const short8*)(Ab + m16 * ASTRIDE + 32 + quad * 8);
        f32x4 accs[4];
#pragma unroll
        for (int t = 0; t < 4; ++t) {
            float bb = b_l[i * ED + t * 16 + m16];
            f32x4 acc = {bb, bb, bb, bb};
            short8 w0 = *(const short8*)(Wlf + (((i * 4 + t) * 2 + 0) * 64 + lane) * 8);
            short8 w1 = *(const short8*)(Wlf + (((i * 4 + t) * 2 + 1) * 64 + lane) * 8);
            acc = __builtin_amdgcn_mfma_f32_16x16x32_bf16(a0b, w0, acc, 0, 0, 0);
            acc = __builtin_amdgcn_mfma_f32_16x16x32_bf16(a1b, w1, acc, 0, 0, 0);
            accs[t] = acc;
        }

        // ---- LayerNorm in D-layout: rows quad*4+r, cols t*16+m16 ----
        float s1[4], s2[4];
#pragma unroll
        for (int r = 0; r < 4; ++r) {
            s1[r] = accs[0][r] + accs[1][r] + accs[2][r] + accs[3][r];
            s2[r] = accs[0][r] * accs[0][r];
            s2[r] = fmaf(accs[1][r], accs[1][r], s2[r]);
            s2[r] = fmaf(accs[2][r], accs[2][r], s2[r]);
            s2[r] = fmaf(accs[3][r], accs[3][r], s2[r]);
        }
#pragma unroll
        for (int d = 1; d <= 8; d <<= 1) {
#pragma unroll
            for (int r = 0; r < 4; ++r) {
                s1[r] += __shfl_xor(s1[r], d, 64);
                s2[r] += __shfl_xor(s2[r], d, 64);
            }
        }
        float gt[4], bt[4];
#pragma unroll
        for (int t = 0; t < 4; ++t) {
            gt[t] = ln_g[i * ED + t * 16 + m16];
            bt[t] = ln_b[i * ED + t * 16 + m16];
        }
#pragma unroll
        for (int r = 0; r < 4; ++r) {
            float mu = s1[r] * (1.0f / 64.0f);
            float var = fmaxf(s2[r] * (1.0f / 64.0f) - mu * mu, 0.0f);
            float rs = rsqrtf(var + 1e-5f);
            int row = quad * 4 + r;
#pragma unroll
            for (int t = 0; t < 4; ++t) {
                float hn = (accs[t][r] - mu) * rs * gt[t] + bt[t];
                Hb[row * HSTR + t * 16 + m16] = hn;   // overwrites A2 (consumed)
            }
        }
        // residual back in lane=channel layout
#pragma unroll
        for (int m = 0; m < 16; ++m) bev[m] = b2[m] + Hb[m * HSTR + lane];
    }

    // ---- z-mean -> block LDS tile -> direct (E, Y*X) output ----
#pragma unroll
    for (int p = 0; p < 2; ++p) {
        float s = 0.0f;
#pragma unroll
        for (int z = 0; z < ZD; ++z) s += bev[p * 8 + z];
        Ob[wv * 2 + p][lane] = s * 0.125f;
    }
    __syncthreads();
    {
        const int q0 = __builtin_amdgcn_readfirstlane(blockIdx.x * 8);
        int t = threadIdx.x;
        int e = t >> 2, pr = t & 3;
        float2 o;
        o.x = Ob[2 * pr + 0][e];
        o.y = Ob[2 * pr + 1][e];
        *(float2*)(out + e * (YD * XD) + q0 + 2 * pr) = o;
    }
}

extern "C" void kernel_launch(void* const* d_in, const int* in_sizes, int n_in,
                              void* d_out, int out_size, void* d_ws, size_t ws_size,
                              hipStream_t stream) {
    const float* Tv      = (const float*)d_in[0];
    const float* intr    = (const float*)d_in[1];
    const float* img     = (const float*)d_in[2];
    const float* bev_in  = (const float*)d_in[3];
    const float* W_off   = (const float*)d_in[4];
    const float* b_off   = (const float*)d_in[5];
    const float* s_off   = (const float*)d_in[6];
    const float* W_w     = (const float*)d_in[7];
    const float* b_w     = (const float*)d_in[8];
    const float* W_l     = (const float*)d_in[9];
    const float* b_l     = (const float*)d_in[10];
    const float* ln_g    = (const float*)d_in[11];
    const float* ln_b    = (const float*)d_in[12];
    float* out = (float*)d_out;

    char* ws = (char*)d_ws;
    float* imgHWC = (float*)ws;                                  // 7,864,320 B
    unsigned short* W9f = (unsigned short*)(ws + 7864320);       // 6,144 B
    unsigned short* Wlf = (unsigned short*)(ws + 7864320 + 6144);// 24,576 B

    // prep: img transpose (480 blocks) + weight frags (8 blocks)
    k_prep<<<(FHD * FWD) / 64 + 8, 256, 0, stream>>>(img, imgHWC, W_off, W_w, W_l,
                                                     W9f, Wlf);
    // main fused loop: 2048 blocks x 4 waves x 2 points; writes (E,Y*X) directly
    k_main<<<(XD * YD) / 8, 256, 0, stream>>>(Tv, intr, imgHWC, bev_in,
                                              W9f, Wlf, b_off, s_off, b_w,
                                              b_l, ln_g, ln_b, out);
}

// Round 7
// 166.169 us; speedup vs baseline: 1.2010x; 1.1975x over previous
//
#include <hip/hip_runtime.h>
#include <math.h>

// Problem constants
#define XD 128
#define YD 128
#define ZD 8
#define ED 64
#define KD 3
#define NITER 3
#define FHD 96
#define FWD 320
#define HALF_W 640.0f
#define HALF_H 192.0f

#define ASTRIDE 80   // shorts per A-tile row (160 B: 16B-aligned; ~zero conflicts measured R3/R4)
#define DSTR 28      // floats per logit-tile row
#define HSTR 68      // floats per H-tile row

// per-wave LDS region offsets (bytes) — R4 layout, Sd shrunk to int2/sample
#define OFF_AB   0       // 16*80*2 = 2560
#define OFF_SD   2560    // 48 int2  = 384
#define OFF_SW   2944    // 48 float4 = 768
#define OFF_DH   3712    // Db (16*28*4=1792) / Hb (16*68*4=4352) union = 4352
#define OFF_CXY  8064    // 32 floats = 128
#define WAVE_LDS 8192

typedef __attribute__((ext_vector_type(8))) short short8;
typedef __attribute__((ext_vector_type(4))) float f32x4;
typedef float          __attribute__((may_alias)) fal;
typedef int            __attribute__((may_alias)) ial;
typedef unsigned short __attribute__((may_alias)) usal;

__device__ __forceinline__ unsigned short f2bf(float f) {
    unsigned u = __float_as_uint(f);
    u += 0x7fff + ((u >> 16) & 1);
    return (unsigned short)(u >> 16);
}

// sum over each 16-lane DPP row via row_ror 1,2,4,8 (pure VALU, no DS pipe)
__device__ __forceinline__ float rowsum16(float v) {
    v += __int_as_float(__builtin_amdgcn_update_dpp(0, __float_as_int(v), 0x121, 0xf, 0xf, true));
    v += __int_as_float(__builtin_amdgcn_update_dpp(0, __float_as_int(v), 0x122, 0xf, 0xf, true));
    v += __int_as_float(__builtin_amdgcn_update_dpp(0, __float_as_int(v), 0x124, 0xf, 0xf, true));
    v += __int_as_float(__builtin_amdgcn_update_dpp(0, __float_as_int(v), 0x128, 0xf, 0xf, true));
    return v;
}

// -------- prep: img CHW->HWC transpose (blocks 0..479) + weight frags + pad ------
__global__ __launch_bounds__(256) void k_prep(const float* __restrict__ img,
                                              float* __restrict__ outHWC,
                                              const float* __restrict__ W_off,
                                              const float* __restrict__ W_w,
                                              const float* __restrict__ W_l,
                                              unsigned short* __restrict__ W9f,
                                              unsigned short* __restrict__ Wlf) {
    if (blockIdx.x < (FHD * FWD) / 64) {
        __shared__ float tile[64][65];
        const int hw0 = blockIdx.x * 64;
        const int lane = threadIdx.x & 63;
        const int r = threadIdx.x >> 6;
#pragma unroll
        for (int i = 0; i < 16; ++i) {
            int e = r + 4 * i;
            tile[e][lane] = img[e * (FHD * FWD) + hw0 + lane];
        }
        __syncthreads();
#pragma unroll
        for (int i = 0; i < 16; ++i) {
            int row = r + 4 * i;
            outHWC[(hw0 + row) * 64 + lane] = tile[lane][row];
        }
    } else {
        int idx = (blockIdx.x - (FHD * FWD) / 64) * 256 + threadIdx.x;
        if (idx < 3 * 4 * 2 * 64) {
            int lane = idx & 63, s = (idx >> 6) & 1, t = (idx >> 7) & 3, i = idx >> 9;
            int n = t * 16 + (lane & 15), quad = lane >> 4;
#pragma unroll
            for (int jj = 0; jj < 8; ++jj) {
                int ep = s * 32 + quad * 8 + jj;
                Wlf[idx * 8 + jj] = f2bf(W_l[(i * ED + ep) * ED + n]);
            }
        } else if (idx < 3 * 4 * 2 * 64 + 3 * 2 * 64) {
            int k = idx - 3 * 4 * 2 * 64;
            int lane = k & 63, s = (k >> 6) & 1, i = k >> 7;
            int n = lane & 15, quad = lane >> 4;
#pragma unroll
            for (int jj = 0; jj < 8; ++jj) {
                int ep = s * 32 + quad * 8 + jj;
                float v = 0.0f;
                if (n < 6) v = W_off[(i * ED + ep) * 6 + n];
                else if (n < 9) v = W_w[(i * ED + ep) * 3 + (n - 6)];
                W9f[k * 8 + jj] = f2bf(v);
            }
        } else if (idx < 3 * 4 * 2 * 64 + 3 * 2 * 64 + 64) {
            // zero the 256 B guard row past imgHWC (read by +1-col loads w/ weight 0)
            outHWC[FHD * FWD * 64 + (idx - (3 * 4 * 2 * 64 + 3 * 2 * 64))] = 0.0f;
        }
    }
}

// -------- main fused kernel: one wave per TWO (x,y) points, 16 MFMA rows --------
__global__ __launch_bounds__(256, 4) void k_main(
    const float* __restrict__ Tv,     // (3,4)
    const float* __restrict__ intr,   // (3,3)
    const float* __restrict__ imgHWC, // (FH*FW, E) + 64-float guard
    const float* __restrict__ bev_in, // (X,Y,Z,E)
    const unsigned short* __restrict__ W9f,
    const unsigned short* __restrict__ Wlf,
    const float* __restrict__ b_off,  // (I,6)
    const float* __restrict__ s_off,  // (I,)
    const float* __restrict__ b_w,    // (I,3)
    const float* __restrict__ b_l,    // (I,E)
    const float* __restrict__ ln_g,   // (I,E)
    const float* __restrict__ ln_b,   // (I,E)
    float* __restrict__ tmp)          // (Y*X, E)
{
    __shared__ __align__(16) char smem[4 * WAVE_LDS];

    const int lane = threadIdx.x & 63;
    const int wv = threadIdx.x >> 6;
    const int wid2 = __builtin_amdgcn_readfirstlane(blockIdx.x * 4 + wv);
    const int m16 = lane & 15;
    const int quad = lane >> 4;
    const int lane4 = lane * 4;

    char* base = smem + wv * WAVE_LDS;
    usal* Ab  = (usal*)(base + OFF_AB);
    ial*  Sd  = (ial*)(base + OFF_SD);
    fal*  Sw  = (fal*)(base + OFF_SW);
    fal*  Db  = (fal*)(base + OFF_DH);
    fal*  Hb  = (fal*)(base + OFF_DH);   // union with Db (serial lifetimes)
    fal*  Cxy = (fal*)(base + OFF_CXY);

    const char* imgB = (const char*)imgHWC;

    // T = intr @ Tv (3x4), uniform
    float T[12];
#pragma unroll
    for (int r = 0; r < 3; ++r)
#pragma unroll
        for (int c = 0; c < 4; ++c)
            T[r * 4 + c] = intr[r * 3 + 0] * Tv[0 * 4 + c] +
                           intr[r * 3 + 1] * Tv[1 * 4 + c] +
                           intr[r * 3 + 2] * Tv[2 * 4 + c];

    // two points per wave; rows m = p*8 + z; cx/cy stashed in LDS
    float bev[16];
#pragma unroll
    for (int p = 0; p < 2; ++p) {
        int q = 2 * wid2 + p;
        int x = q & (XD - 1);
        int y = q >> 7;
        float gx = x * 0.8f;
        float gy = 51.2f - y * 0.8f;
        int pbase = (((x << 7) | y) << 9);
#pragma unroll
        for (int z = 0; z < ZD; ++z) {
            float gz = z * 0.5f - 2.5f;
            float p0 = T[0] * gx + T[1] * gy + T[2] * gz + T[3];
            float p1 = T[4] * gx + T[5] * gy + T[6] * gz + T[7];
            float p2 = T[8] * gx + T[9] * gy + T[10] * gz + T[11];
            float cxv = (p0 / p2) / HALF_W - 1.0f;
            float cyv = (p1 / p2) / HALF_H - 1.0f;
            int m = p * 8 + z;
            if (lane == 0) {
                Cxy[m * 2 + 0] = cxv;
                Cxy[m * 2 + 1] = cyv;
            }
            bev[m] = bev_in[pbase + z * ED + lane];
        }
    }

    for (int i = 0; i < NITER; ++i) {
        // ---- stage 1: logits = bev(16x64) @ W9(64x9) via 2 MFMAs ----
#pragma unroll
        for (int m = 0; m < 16; ++m) Ab[m * ASTRIDE + lane] = f2bf(bev[m]);

        short8 wb0 = *(const short8*)(W9f + ((i * 2 + 0) * 64 + lane) * 8);
        short8 wb1 = *(const short8*)(W9f + ((i * 2 + 1) * 64 + lane) * 8);
        short8 a0 = *(const short8*)(Ab + m16 * ASTRIDE + quad * 8);
        short8 a1 = *(const short8*)(Ab + m16 * ASTRIDE + 32 + quad * 8);
        f32x4 dlog = {0.0f, 0.0f, 0.0f, 0.0f};
        dlog = __builtin_amdgcn_mfma_f32_16x16x32_bf16(a0, wb0, dlog, 0, 0, 0);
        dlog = __builtin_amdgcn_mfma_f32_16x16x32_bf16(a1, wb1, dlog, 0, 0, 0);
#pragma unroll
        for (int r = 0; r < 4; ++r) Db[(quad * 4 + r) * DSTR + m16] = dlog[r];

        const float so = s_off[i];
        const float bo0 = b_off[i * 6 + 0], bo1 = b_off[i * 6 + 1], bo2 = b_off[i * 6 + 2];
        const float bo3 = b_off[i * 6 + 3], bo4 = b_off[i * 6 + 4], bo5 = b_off[i * 6 + 5];
        const float bw0 = b_w[i * 3 + 0], bw1 = b_w[i * 3 + 1], bw2 = b_w[i * 3 + 2];

        // ---- lane-parallel sample descriptors (48 lanes = 16 rows x 3 k) ----
        // Per sample: two ROW ids (y0,y1) at base column cb; the +1 column is read
        // via a +256 B immediate offset; x-edge validity folded into weights.
        if (lane < 48) {
            int m = lane / 3;
            int k = lane - m * 3;
            const fal* Dm = Db + m * DSTR;
            f32x4 qa = *(const f32x4*)(Dm);       // logits 0..3
            f32x4 qb = *(const f32x4*)(Dm + 4);   // logits 4..7
            float l8 = Dm[8];

            float ox0 = (qa[0] + bo0) * so, oy0 = (qa[1] + bo1) * so;
            float ox1 = (qa[2] + bo2) * so, oy1 = (qa[3] + bo3) * so;
            float ox2 = (qb[0] + bo4) * so, oy2 = (qb[1] + bo5) * so;
            float l0 = qb[2] + bw0, l1 = qb[3] + bw1, l2 = l8 + bw2;
            float mx = fmaxf(fmaxf(l0, l1), l2);
            float e0 = __expf(l0 - mx), e1 = __expf(l1 - mx), e2 = __expf(l2 - mx);
            float inv = 1.0f / (e0 + e1 + e2);
            float wk0 = e0 * inv, wk1 = e1 * inv, wk2 = e2 * inv;

            float wkk = (k == 0) ? wk0 : ((k == 1) ? wk1 : wk2);
            float ox  = (k == 0) ? ox0 : ((k == 1) ? ox1 : ox2);
            float oy  = (k == 0) ? oy0 : ((k == 1) ? oy1 : oy2);

            float cxf = Cxy[m * 2 + 0], cyf = Cxy[m * 2 + 1];
            float gxx = cxf + ox, gyy = cyf + oy;
            float px = ((gxx + 1.0f) * (float)FWD - 1.0f) * 0.5f;
            float py = ((gyy + 1.0f) * (float)FHD - 1.0f) * 0.5f;
            float x0f = floorf(px), y0f = floorf(py);
            float fx = px - x0f, fy = py - y0f;
            int ix0 = (int)x0f, iy0 = (int)y0f;
            int iy1 = iy0 + 1;

            int cb = min(max(ix0, 0), FWD - 1);
            float wA = (ix0 >= 0 && ix0 < FWD) ? (1.0f - fx)
                                               : ((ix0 == -1) ? fx : 0.0f);
            float wB = (ix0 >= 0 && ix0 + 1 < FWD) ? fx : 0.0f;

            int rb0 = min(max(iy0, 0), FHD - 1);
            int rb1 = min(max(iy1, 0), FHD - 1);
            float wy0v = (iy0 >= 0 && iy0 < FHD) ? (1.0f - fy) : 0.0f;
            float wy1v = (iy1 >= 0 && iy1 < FHD) ? fy : 0.0f;

            ial* sd = Sd + lane * 2;
            sd[0] = rb0 * FWD + cb;
            sd[1] = rb1 * FWD + cb;
            fal* sw = Sw + lane * 4;
            sw[0] = wkk * wA * wy0v;
            sw[1] = wkk * wB * wy0v;
            sw[2] = wkk * wA * wy1v;
            sw[3] = wkk * wB * wy1v;
        }

        // ---- sampling: scalar (SGPR) bases + shared lane voffset + imm offsets ----
        float b2[16];
#pragma unroll
        for (int m = 0; m < 16; ++m) {
            float feat = 0.0f;
#pragma unroll
            for (int k = 0; k < KD; ++k) {
                int s = m * 3 + k;
                int2 id = *(const int2*)(Sd + s * 2);
                float4 w4 = *(const float4*)(Sw + s * 4);
                int offA = __builtin_amdgcn_readfirstlane(id.x) << 8;
                int offB = __builtin_amdgcn_readfirstlane(id.y) << 8;
                const fal* pA = (const fal*)(imgB + offA + lane4);
                const fal* pB = (const fal*)(imgB + offB + lane4);
                feat = fmaf(w4.x, pA[0], feat);
                feat = fmaf(w4.y, pA[64], feat);   // +256 B imm (next column)
                feat = fmaf(w4.z, pB[0], feat);
                feat = fmaf(w4.w, pB[64], feat);
            }
            b2[m] = bev[m] + feat;  // bev_mid
        }

        // ---- stage 2: h = bev_mid(16x64) @ W_l + b_l via 8 MFMAs ----
#pragma unroll
        for (int m = 0; m < 16; ++m) Ab[m * ASTRIDE + lane] = f2bf(b2[m]);
        short8 a0b = *(const short8*)(Ab + m16 * ASTRIDE + quad * 8);
        short8 a1b = *(const short8*)(Ab + m16 * ASTRIDE + 32 + quad * 8);
        f32x4 accs[4];
#pragma unroll
        for (int t = 0; t < 4; ++t) {
            float bb = b_l[i * ED + t * 16 + m16];
            f32x4 acc = {bb, bb, bb, bb};
            short8 w0 = *(const short8*)(Wlf + (((i * 4 + t) * 2 + 0) * 64 + lane) * 8);
            short8 w1 = *(const short8*)(Wlf + (((i * 4 + t) * 2 + 1) * 64 + lane) * 8);
            acc = __builtin_amdgcn_mfma_f32_16x16x32_bf16(a0b, w0, acc, 0, 0, 0);
            acc = __builtin_amdgcn_mfma_f32_16x16x32_bf16(a1b, w1, acc, 0, 0, 0);
            accs[t] = acc;
        }

        // ---- LayerNorm in D-layout: rows quad*4+r, cols t*16+m16 (DPP row-sums) ----
        float s1[4], s2[4];
#pragma unroll
        for (int r = 0; r < 4; ++r) {
            s1[r] = accs[0][r] + accs[1][r] + accs[2][r] + accs[3][r];
            s2[r] = accs[0][r] * accs[0][r];
            s2[r] = fmaf(accs[1][r], accs[1][r], s2[r]);
            s2[r] = fmaf(accs[2][r], accs[2][r], s2[r]);
            s2[r] = fmaf(accs[3][r], accs[3][r], s2[r]);
            s1[r] = rowsum16(s1[r]);
            s2[r] = rowsum16(s2[r]);
        }
        float gt[4], bt[4];
#pragma unroll
        for (int t = 0; t < 4; ++t) {
            gt[t] = ln_g[i * ED + t * 16 + m16];
            bt[t] = ln_b[i * ED + t * 16 + m16];
        }
#pragma unroll
        for (int r = 0; r < 4; ++r) {
            float mu = s1[r] * (1.0f / 64.0f);
            float var = fmaxf(s2[r] * (1.0f / 64.0f) - mu * mu, 0.0f);
            float rs = rsqrtf(var + 1e-5f);
            int row = quad * 4 + r;
#pragma unroll
            for (int t = 0; t < 4; ++t) {
                float hn = (accs[t][r] - mu) * rs * gt[t] + bt[t];
                Hb[row * HSTR + t * 16 + m16] = hn;
            }
        }
        // residual back in lane=channel layout
#pragma unroll
        for (int m = 0; m < 16; ++m) bev[m] = b2[m] + Hb[m * HSTR + lane];
    }

    // z-mean, write two tmp rows (coalesced; transpose kernel finishes layout)
#pragma unroll
    for (int p = 0; p < 2; ++p) {
        float s = 0.0f;
#pragma unroll
        for (int z = 0; z < ZD; ++z) s += bev[p * 8 + z];
        tmp[(2 * wid2 + p) * ED + lane] = s * 0.125f;
    }
}

// tmp (Y*X, E) -> out (E, Y*X) via LDS tile transpose (fully coalesced both ways)
__global__ __launch_bounds__(256) void k_transpose(const float* __restrict__ tmp,
                                                   float* __restrict__ out) {
    __shared__ float tile[64][65];
    const int p0 = blockIdx.x * 64;
    const int lane = threadIdx.x & 63;
    const int r = threadIdx.x >> 6;
#pragma unroll
    for (int i = 0; i < 16; ++i) {
        int row = r + 4 * i;
        tile[row][lane] = tmp[(p0 + row) * ED + lane];
    }
    __syncthreads();
#pragma unroll
    for (int i = 0; i < 16; ++i) {
        int erow = r + 4 * i;
        out[erow * (YD * XD) + p0 + lane] = tile[lane][erow];
    }
}

extern "C" void kernel_launch(void* const* d_in, const int* in_sizes, int n_in,
                              void* d_out, int out_size, void* d_ws, size_t ws_size,
                              hipStream_t stream) {
    const float* Tv      = (const float*)d_in[0];
    const float* intr    = (const float*)d_in[1];
    const float* img     = (const float*)d_in[2];
    const float* bev_in  = (const float*)d_in[3];
    const float* W_off   = (const float*)d_in[4];
    const float* b_off   = (const float*)d_in[5];
    const float* s_off   = (const float*)d_in[6];
    const float* W_w     = (const float*)d_in[7];
    const float* b_w     = (const float*)d_in[8];
    const float* W_l     = (const float*)d_in[9];
    const float* b_l     = (const float*)d_in[10];
    const float* ln_g    = (const float*)d_in[11];
    const float* ln_b    = (const float*)d_in[12];
    float* out = (float*)d_out;

    char* ws = (char*)d_ws;
    float* imgHWC = (float*)ws;                                // 7,864,320 B + 256 B guard
    float* tmp = (float*)(ws + 7864576);                       // 4,194,304 B
    unsigned short* W9f = (unsigned short*)(ws + 7864576 + 4194304);        // 6,144 B
    unsigned short* Wlf = (unsigned short*)(ws + 7864576 + 4194304 + 6144); // 24,576 B

    // prep: img transpose (480 blocks) + weight frags + guard zero (8 blocks)
    k_prep<<<(FHD * FWD) / 64 + 8, 256, 0, stream>>>(img, imgHWC, W_off, W_w, W_l,
                                                     W9f, Wlf);
    // main fused loop: 8192 waves, 2 points each; coalesced tmp writes
    k_main<<<(XD * YD / 2) / 4, 256, 0, stream>>>(Tv, intr, imgHWC, bev_in,
                                                  W9f, Wlf, b_off, s_off, b_w,
                                                  b_l, ln_g, ln_b, tmp);
    // transpose (Y*X,E) -> (E,Y*X)
    k_transpose<<<(YD * XD) / 64, 256, 0, stream>>>(tmp, out);
}

// Round 8
// 164.391 us; speedup vs baseline: 1.2140x; 1.0108x over previous
//
#include <hip/hip_runtime.h>
#include <math.h>

// Problem constants
#define XD 128
#define YD 128
#define ZD 8
#define ED 64
#define KD 3
#define NITER 3
#define FHD 96
#define FWD 320
#define HALF_W 640.0f
#define HALF_H 192.0f

#define ASTRIDE 80   // shorts per A-tile row (160 B: 16B-aligned; ~zero conflicts R3/R4/R7)
#define DSTR 28      // floats per logit-tile row
#define HSTR 68      // floats per H-tile row

// Single per-wave LDS UNION region (serial wave-private lifetimes, in-order DS):
//   Ab bf16 A-tile (16*80*2 = 2560 B)  ->  Db logits (16*28*4 = 1792 B)
//   -> Ab (stage 2) -> Hb (16*68*4 = 4352 B)
#define WAVE_LDS 4352

typedef __attribute__((ext_vector_type(8))) short short8;
typedef __attribute__((ext_vector_type(4))) float f32x4;
typedef float          __attribute__((may_alias)) fal;
typedef unsigned short __attribute__((may_alias)) usal;

__device__ __forceinline__ unsigned short f2bf(float f) {
    unsigned u = __float_as_uint(f);
    u += 0x7fff + ((u >> 16) & 1);
    return (unsigned short)(u >> 16);
}

__device__ __forceinline__ float rdlane_f(float v, int s) {
    return __int_as_float(__builtin_amdgcn_readlane(__float_as_int(v), s));
}

// sum over each 16-lane DPP row via row_ror 1,2,4,8 (pure VALU, no DS pipe)
__device__ __forceinline__ float rowsum16(float v) {
    v += __int_as_float(__builtin_amdgcn_update_dpp(0, __float_as_int(v), 0x121, 0xf, 0xf, true));
    v += __int_as_float(__builtin_amdgcn_update_dpp(0, __float_as_int(v), 0x122, 0xf, 0xf, true));
    v += __int_as_float(__builtin_amdgcn_update_dpp(0, __float_as_int(v), 0x124, 0xf, 0xf, true));
    v += __int_as_float(__builtin_amdgcn_update_dpp(0, __float_as_int(v), 0x128, 0xf, 0xf, true));
    return v;
}

// -------- prep: img CHW->HWC transpose (blocks 0..479) + weight frags + pad ------
__global__ __launch_bounds__(256) void k_prep(const float* __restrict__ img,
                                              float* __restrict__ outHWC,
                                              const float* __restrict__ W_off,
                                              const float* __restrict__ W_w,
                                              const float* __restrict__ W_l,
                                              unsigned short* __restrict__ W9f,
                                              unsigned short* __restrict__ Wlf) {
    if (blockIdx.x < (FHD * FWD) / 64) {
        __shared__ float tile[64][65];
        const int hw0 = blockIdx.x * 64;
        const int lane = threadIdx.x & 63;
        const int r = threadIdx.x >> 6;
#pragma unroll
        for (int i = 0; i < 16; ++i) {
            int e = r + 4 * i;
            tile[e][lane] = img[e * (FHD * FWD) + hw0 + lane];
        }
        __syncthreads();
#pragma unroll
        for (int i = 0; i < 16; ++i) {
            int row = r + 4 * i;
            outHWC[(hw0 + row) * 64 + lane] = tile[lane][row];
        }
    } else {
        int idx = (blockIdx.x - (FHD * FWD) / 64) * 256 + threadIdx.x;
        if (idx < 3 * 4 * 2 * 64) {
            int lane = idx & 63, s = (idx >> 6) & 1, t = (idx >> 7) & 3, i = idx >> 9;
            int n = t * 16 + (lane & 15), quad = lane >> 4;
#pragma unroll
            for (int jj = 0; jj < 8; ++jj) {
                int ep = s * 32 + quad * 8 + jj;
                Wlf[idx * 8 + jj] = f2bf(W_l[(i * ED + ep) * ED + n]);
            }
        } else if (idx < 3 * 4 * 2 * 64 + 3 * 2 * 64) {
            int k = idx - 3 * 4 * 2 * 64;
            int lane = k & 63, s = (k >> 6) & 1, i = k >> 7;
            int n = lane & 15, quad = lane >> 4;
#pragma unroll
            for (int jj = 0; jj < 8; ++jj) {
                int ep = s * 32 + quad * 8 + jj;
                float v = 0.0f;
                if (n < 6) v = W_off[(i * ED + ep) * 6 + n];
                else if (n < 9) v = W_w[(i * ED + ep) * 3 + (n - 6)];
                W9f[k * 8 + jj] = f2bf(v);
            }
        } else if (idx < 3 * 4 * 2 * 64 + 3 * 2 * 64 + 64) {
            // zero the 256 B guard row past imgHWC (read by +1-col loads w/ weight 0)
            outHWC[FHD * FWD * 64 + (idx - (3 * 4 * 2 * 64 + 3 * 2 * 64))] = 0.0f;
        }
    }
}

// -------- main fused kernel: one wave per TWO (x,y) points, 16 MFMA rows --------
__global__ __launch_bounds__(256, 4) void k_main(
    const float* __restrict__ Tv,     // (3,4)
    const float* __restrict__ intr,   // (3,3)
    const float* __restrict__ imgHWC, // (FH*FW, E) + 64-float guard
    const float* __restrict__ bev_in, // (X,Y,Z,E)
    const unsigned short* __restrict__ W9f,
    const unsigned short* __restrict__ Wlf,
    const float* __restrict__ b_off,  // (I,6)
    const float* __restrict__ s_off,  // (I,)
    const float* __restrict__ b_w,    // (I,3)
    const float* __restrict__ b_l,    // (I,E)
    const float* __restrict__ ln_g,   // (I,E)
    const float* __restrict__ ln_b,   // (I,E)
    float* __restrict__ tmp)          // (Y*X, E)
{
    __shared__ __align__(16) char smem[4 * WAVE_LDS];

    const int lane = threadIdx.x & 63;
    const int wv = threadIdx.x >> 6;
    const int wid2 = __builtin_amdgcn_readfirstlane(blockIdx.x * 4 + wv);
    const int m16 = lane & 15;
    const int quad = lane >> 4;

    char* base = smem + wv * WAVE_LDS;
    usal* Ab = (usal*)base;
    fal*  Db = (fal*)base;
    fal*  Hb = (fal*)base;

    const char* imgB = (const char*)imgHWC;

    // T = intr @ Tv (3x4), uniform
    float T[12];
#pragma unroll
    for (int r = 0; r < 3; ++r)
#pragma unroll
        for (int c = 0; c < 4; ++c)
            T[r * 4 + c] = intr[r * 3 + 0] * Tv[0 * 4 + c] +
                           intr[r * 3 + 1] * Tv[1 * 4 + c] +
                           intr[r * 3 + 2] * Tv[2 * 4 + c];

    // per-lane descriptor identity: lane s handles sample (m = s/3, k = s%3), s<48
    const int sm = min(lane / 3, 15);
    const int sk = lane - (lane / 3) * 3;

    // per-lane projected base coords for row sm
    float cxd, cyd;
    {
        int p = sm >> 3, z = sm & 7;
        int q = 2 * wid2 + p;
        int x = q & (XD - 1);
        int y = q >> 7;
        float gx = x * 0.8f;
        float gy = 51.2f - y * 0.8f;
        float gz = z * 0.5f - 2.5f;
        float p0 = T[0] * gx + T[1] * gy + T[2] * gz + T[3];
        float p1 = T[4] * gx + T[5] * gy + T[6] * gz + T[7];
        float p2 = T[8] * gx + T[9] * gy + T[10] * gz + T[11];
        cxd = (p0 / p2) / HALF_W - 1.0f;
        cyd = (p1 / p2) / HALF_H - 1.0f;
    }

    // two points per wave; rows m = p*8 + z
    float bev[16];
#pragma unroll
    for (int p = 0; p < 2; ++p) {
        int q = 2 * wid2 + p;
        int x = q & (XD - 1);
        int y = q >> 7;
        int pbase = (((x << 7) | y) << 9);
#pragma unroll
        for (int z = 0; z < ZD; ++z)
            bev[p * 8 + z] = bev_in[pbase + z * ED + lane];
    }

    for (int i = 0; i < NITER; ++i) {
        // ---- stage 1: logits = bev(16x64) @ W9(64x9) via 2 MFMAs ----
#pragma unroll
        for (int m = 0; m < 16; ++m) Ab[m * ASTRIDE + lane] = f2bf(bev[m]);

        short8 wb0 = *(const short8*)(W9f + ((i * 2 + 0) * 64 + lane) * 8);
        short8 wb1 = *(const short8*)(W9f + ((i * 2 + 1) * 64 + lane) * 8);
        short8 a0 = *(const short8*)(Ab + m16 * ASTRIDE + quad * 8);
        short8 a1 = *(const short8*)(Ab + m16 * ASTRIDE + 32 + quad * 8);
        f32x4 dlog = {0.0f, 0.0f, 0.0f, 0.0f};
        dlog = __builtin_amdgcn_mfma_f32_16x16x32_bf16(a0, wb0, dlog, 0, 0, 0);
        dlog = __builtin_amdgcn_mfma_f32_16x16x32_bf16(a1, wb1, dlog, 0, 0, 0);
        // D-layout -> Db (overwrites A-tile region; A already consumed)
#pragma unroll
        for (int r = 0; r < 4; ++r) Db[(quad * 4 + r) * DSTR + m16] = dlog[r];

        const float so = s_off[i];
        const float bo0 = b_off[i * 6 + 0], bo1 = b_off[i * 6 + 1], bo2 = b_off[i * 6 + 2];
        const float bo3 = b_off[i * 6 + 3], bo4 = b_off[i * 6 + 4], bo5 = b_off[i * 6 + 5];
        const float bw0 = b_w[i * 3 + 0], bw1 = b_w[i * 3 + 1], bw2 = b_w[i * 3 + 2];

        // ---- lane-parallel sample descriptors, kept in REGISTERS ----
        int rowA, rowB;
        float dw0, dw1, dw2, dw3;
        {
            const fal* Dm = Db + sm * DSTR;
            f32x4 qa = *(const f32x4*)(Dm);       // logits 0..3
            f32x4 qb = *(const f32x4*)(Dm + 4);   // logits 4..7
            float l8 = Dm[8];

            float ox0 = (qa[0] + bo0) * so, oy0 = (qa[1] + bo1) * so;
            float ox1 = (qa[2] + bo2) * so, oy1 = (qa[3] + bo3) * so;
            float ox2 = (qb[0] + bo4) * so, oy2 = (qb[1] + bo5) * so;
            float l0 = qb[2] + bw0, l1 = qb[3] + bw1, l2 = l8 + bw2;
            float mx = fmaxf(fmaxf(l0, l1), l2);
            float e0 = __expf(l0 - mx), e1 = __expf(l1 - mx), e2 = __expf(l2 - mx);
            float inv = 1.0f / (e0 + e1 + e2);
            float wk0 = e0 * inv, wk1 = e1 * inv, wk2 = e2 * inv;

            float wkk = (sk == 0) ? wk0 : ((sk == 1) ? wk1 : wk2);
            float ox  = (sk == 0) ? ox0 : ((sk == 1) ? ox1 : ox2);
            float oy  = (sk == 0) ? oy0 : ((sk == 1) ? oy1 : oy2);

            float gxx = cxd + ox, gyy = cyd + oy;
            float px = ((gxx + 1.0f) * (float)FWD - 1.0f) * 0.5f;
            float py = ((gyy + 1.0f) * (float)FHD - 1.0f) * 0.5f;
            float x0f = floorf(px), y0f = floorf(py);
            float fx = px - x0f, fy = py - y0f;
            int ix0 = (int)x0f, iy0 = (int)y0f;
            int iy1 = iy0 + 1;

            int cb = min(max(ix0, 0), FWD - 1);
            float wA = (ix0 >= 0 && ix0 < FWD) ? (1.0f - fx)
                                               : ((ix0 == -1) ? fx : 0.0f);
            float wB = (ix0 >= 0 && ix0 + 1 < FWD) ? fx : 0.0f;

            int rb0 = min(max(iy0, 0), FHD - 1);
            int rb1 = min(max(iy1, 0), FHD - 1);
            float wy0v = (iy0 >= 0 && iy0 < FHD) ? (1.0f - fy) : 0.0f;
            float wy1v = (iy1 >= 0 && iy1 < FHD) ? fy : 0.0f;

            rowA = rb0 * FWD + cb;
            rowB = rb1 * FWD + cb;
            dw0 = wkk * wA * wy0v;
            dw1 = wkk * wB * wy0v;
            dw2 = wkk * wA * wy1v;
            dw3 = wkk * wB * wy1v;
        }

        // ---- sampling: v_readlane broadcast -> SGPR bases/weights, no LDS ----
        float b2[16];
#pragma unroll
        for (int m = 0; m < 16; ++m) {
            float feat = 0.0f;
#pragma unroll
            for (int k = 0; k < KD; ++k) {
                const int s = m * 3 + k;
                int offA = __builtin_amdgcn_readlane(rowA, s);
                int offB = __builtin_amdgcn_readlane(rowB, s);
                float w0 = rdlane_f(dw0, s);
                float w1 = rdlane_f(dw1, s);
                float w2 = rdlane_f(dw2, s);
                float w3 = rdlane_f(dw3, s);
                const fal* pA = (const fal*)(imgB + ((size_t)(unsigned)offA << 8)) + lane;
                const fal* pB = (const fal*)(imgB + ((size_t)(unsigned)offB << 8)) + lane;
                float vA0 = pA[0], vA1 = pA[64];   // +256 B imm (next column)
                float vB0 = pB[0], vB1 = pB[64];
                feat = fmaf(w0, vA0, feat);
                feat = fmaf(w1, vA1, feat);
                feat = fmaf(w2, vB0, feat);
                feat = fmaf(w3, vB1, feat);
            }
            b2[m] = bev[m] + feat;  // bev_mid
        }

        // ---- stage 2: h = bev_mid(16x64) @ W_l + b_l via 8 MFMAs ----
#pragma unroll
        for (int m = 0; m < 16; ++m) Ab[m * ASTRIDE + lane] = f2bf(b2[m]);
        short8 a0b = *(const short8*)(Ab + m16 * ASTRIDE + quad * 8);
        short8 a1b = *(const short8*)(Ab + m16 * ASTRIDE + 32 + quad * 8);
        f32x4 accs[4];
#pragma unroll
        for (int t = 0; t < 4; ++t) {
            float bb = b_l[i * ED + t * 16 + m16];
            f32x4 acc = {bb, bb, bb, bb};
            short8 w0 = *(const short8*)(Wlf + (((i * 4 + t) * 2 + 0) * 64 + lane) * 8);
            short8 w1 = *(const short8*)(Wlf + (((i * 4 + t) * 2 + 1) * 64 + lane) * 8);
            acc = __builtin_amdgcn_mfma_f32_16x16x32_bf16(a0b, w0, acc, 0, 0, 0);
            acc = __builtin_amdgcn_mfma_f32_16x16x32_bf16(a1b, w1, acc, 0, 0, 0);
            accs[t] = acc;
        }

        // ---- LayerNorm in D-layout: rows quad*4+r, cols t*16+m16 (DPP row-sums) ----
        float s1[4], s2[4];
#pragma unroll
        for (int r = 0; r < 4; ++r) {
            s1[r] = accs[0][r] + accs[1][r] + accs[2][r] + accs[3][r];
            s2[r] = accs[0][r] * accs[0][r];
            s2[r] = fmaf(accs[1][r], accs[1][r], s2[r]);
            s2[r] = fmaf(accs[2][r], accs[2][r], s2[r]);
            s2[r] = fmaf(accs[3][r], accs[3][r], s2[r]);
            s1[r] = rowsum16(s1[r]);
            s2[r] = rowsum16(s2[r]);
        }
        float gt[4], bt[4];
#pragma unroll
        for (int t = 0; t < 4; ++t) {
            gt[t] = ln_g[i * ED + t * 16 + m16];
            bt[t] = ln_b[i * ED + t * 16 + m16];
        }
#pragma unroll
        for (int r = 0; r < 4; ++r) {
            float mu = s1[r] * (1.0f / 64.0f);
            float var = fmaxf(s2[r] * (1.0f / 64.0f) - mu * mu, 0.0f);
            float rs = rsqrtf(var + 1e-5f);
            int row = quad * 4 + r;
#pragma unroll
            for (int t = 0; t < 4; ++t) {
                float hn = (accs[t][r] - mu) * rs * gt[t] + bt[t];
                Hb[row * HSTR + t * 16 + m16] = hn;   // overwrites A2 (consumed)
            }
        }
        // residual back in lane=channel layout
#pragma unroll
        for (int m = 0; m < 16; ++m) bev[m] = b2[m] + Hb[m * HSTR + lane];
    }

    // z-mean, write two tmp rows (coalesced; transpose kernel finishes layout)
#pragma unroll
    for (int p = 0; p < 2; ++p) {
        float s = 0.0f;
#pragma unroll
        for (int z = 0; z < ZD; ++z) s += bev[p * 8 + z];
        tmp[(2 * wid2 + p) * ED + lane] = s * 0.125f;
    }
}

// tmp (Y*X, E) -> out (E, Y*X) via LDS tile transpose (fully coalesced both ways)
__global__ __launch_bounds__(256) void k_transpose(const float* __restrict__ tmp,
                                                   float* __restrict__ out) {
    __shared__ float tile[64][65];
    const int p0 = blockIdx.x * 64;
    const int lane = threadIdx.x & 63;
    const int r = threadIdx.x >> 6;
#pragma unroll
    for (int i = 0; i < 16; ++i) {
        int row = r + 4 * i;
        tile[row][lane] = tmp[(p0 + row) * ED + lane];
    }
    __syncthreads();
#pragma unroll
    for (int i = 0; i < 16; ++i) {
        int erow = r + 4 * i;
        out[erow * (YD * XD) + p0 + lane] = tile[lane][erow];
    }
}

extern "C" void kernel_launch(void* const* d_in, const int* in_sizes, int n_in,
                              void* d_out, int out_size, void* d_ws, size_t ws_size,
                              hipStream_t stream) {
    const float* Tv      = (const float*)d_in[0];
    const float* intr    = (const float*)d_in[1];
    const float* img     = (const float*)d_in[2];
    const float* bev_in  = (const float*)d_in[3];
    const float* W_off   = (const float*)d_in[4];
    const float* b_off   = (const float*)d_in[5];
    const float* s_off   = (const float*)d_in[6];
    const float* W_w     = (const float*)d_in[7];
    const float* b_w     = (const float*)d_in[8];
    const float* W_l     = (const float*)d_in[9];
    const float* b_l     = (const float*)d_in[10];
    const float* ln_g    = (const float*)d_in[11];
    const float* ln_b    = (const float*)d_in[12];
    float* out = (float*)d_out;

    char* ws = (char*)d_ws;
    float* imgHWC = (float*)ws;                                // 7,864,320 B + 256 B guard
    float* tmp = (float*)(ws + 7864576);                       // 4,194,304 B
    unsigned short* W9f = (unsigned short*)(ws + 7864576 + 4194304);        // 6,144 B
    unsigned short* Wlf = (unsigned short*)(ws + 7864576 + 4194304 + 6144); // 24,576 B

    // prep: img transpose (480 blocks) + weight frags + guard zero (8 blocks)
    k_prep<<<(FHD * FWD) / 64 + 8, 256, 0, stream>>>(img, imgHWC, W_off, W_w, W_l,
                                                     W9f, Wlf);
    // main fused loop: 8192 waves, 2 points each; coalesced tmp writes
    k_main<<<(XD * YD / 2) / 4, 256, 0, stream>>>(Tv, intr, imgHWC, bev_in,
                                                  W9f, Wlf, b_off, s_off, b_w,
                                                  b_l, ln_g, ln_b, tmp);
    // transpose (Y*X,E) -> (E,Y*X)
    k_transpose<<<(YD * XD) / 64, 256, 0, stream>>>(tmp, out);
}